// Round 1
// baseline (1073.009 us; speedup 1.0000x reference)
//
#include <hip/hip_runtime.h>
#include <hip/hip_bf16.h>
#include <math.h>

typedef __bf16 bf16x8 __attribute__((ext_vector_type(8)));
typedef float  f32x4  __attribute__((ext_vector_type(4)));

#define GLD16(g, l) __builtin_amdgcn_global_load_lds(                      \
    (const __attribute__((address_space(1))) void*)(g),                    \
    (__attribute__((address_space(3))) void*)(l), 16, 0, 0)

// ---------------- transpose + f32 -> bf16 convert (out[c][r] = in[r][c]) ----
__global__ __launch_bounds__(256) void tconv_k(const float* __restrict__ in,
                                               __bf16* __restrict__ out,
                                               int ldin, int ldout) {
  __shared__ float t[32][33];
  int c0 = blockIdx.x * 32, r0 = blockIdx.y * 32;
  int tx = threadIdx.x & 31, ty = threadIdx.x >> 5;
  #pragma unroll
  for (int i = ty; i < 32; i += 8)
    t[i][tx] = in[(size_t)(r0 + i) * ldin + c0 + tx];
  __syncthreads();
  #pragma unroll
  for (int i = ty; i < 32; i += 8)
    out[(size_t)(c0 + i) * ldout + r0 + tx] = (__bf16)t[tx][i];
}

// ---------------- RMSNorm: x = h * rsqrt(mean(h^2) + eps), bf16 out --------
__global__ __launch_bounds__(256) void rmsnorm_k(const float* __restrict__ hs,
                                                 __bf16* __restrict__ x) {
  int row = blockIdx.x, tid = threadIdx.x;
  const float4 v = ((const float4*)(hs + (size_t)row * 1024))[tid];
  float ss = v.x * v.x + v.y * v.y + v.z * v.z + v.w * v.w;
  #pragma unroll
  for (int o = 32; o > 0; o >>= 1) ss += __shfl_xor(ss, o);
  __shared__ float ps[4];
  if ((tid & 63) == 0) ps[tid >> 6] = ss;
  __syncthreads();
  float tot = ps[0] + ps[1] + ps[2] + ps[3];
  float r = rsqrtf(tot * (1.0f / 1024.0f) + 1.1920929e-7f);
  __bf16* xr = x + (size_t)row * 1024 + tid * 4;
  xr[0] = (__bf16)(v.x * r); xr[1] = (__bf16)(v.y * r);
  xr[2] = (__bf16)(v.z * r); xr[3] = (__bf16)(v.w * r);
}

// ---------------- GEMM: C(MxN,f32) = A(MxK,bf16) * Bt(NxK,bf16)^T ----------
// m97 structure: 128x128 tile, 4 waves, 16x16x32 bf16 MFMA, global_load_lds.
// Optional epilogue: +bias[col], +add1[idx], +lam*addh[idx]
__global__ __launch_bounds__(256) void gemm_bt_k(
    const __bf16* __restrict__ A, const __bf16* __restrict__ Bt,
    float* __restrict__ C, int N, int K,
    const float* __restrict__ bias, const float* __restrict__ add1,
    const float* __restrict__ addh, const float* __restrict__ plam) {
  __shared__ __bf16 sA[128 * 32];
  __shared__ __bf16 sB[128 * 32];
  const int tid = threadIdx.x;
  const int lane = tid & 63;
  const int quad = lane >> 4, l16 = lane & 15;
  const int wave = tid >> 6;
  const int waveM = wave >> 1, waveN = wave & 1;
  const int m0 = blockIdx.y * 128, n0 = blockIdx.x * 128;
  const int rowS = tid >> 2;
  const int kgS = (tid & 3) * 8;
  const __bf16* gA0 = A + (size_t)(m0 + rowS) * K + kgS;
  const __bf16* gA1 = gA0 + (size_t)64 * K;
  const __bf16* gB0 = Bt + (size_t)(n0 + rowS) * K + kgS;
  const __bf16* gB1 = gB0 + (size_t)64 * K;
  __bf16* lA0 = sA + tid * 8; __bf16* lA1 = sA + 2048 + tid * 8;
  __bf16* lB0 = sB + tid * 8; __bf16* lB1 = sB + 2048 + tid * 8;
  f32x4 acc[4][4] = {};
  for (int k0 = 0; k0 < K; k0 += 32) {
    GLD16(gA0 + k0, lA0);
    GLD16(gA1 + k0, lA1);
    GLD16(gB0 + k0, lB0);
    GLD16(gB1 + k0, lB1);
    __syncthreads();
    bf16x8 af[4], bfv[4];
    #pragma unroll
    for (int mt = 0; mt < 4; ++mt)
      af[mt] = *(const bf16x8*)(sA + (waveM * 64 + mt * 16 + l16) * 32 + quad * 8);
    #pragma unroll
    for (int nt = 0; nt < 4; ++nt)
      bfv[nt] = *(const bf16x8*)(sB + (waveN * 64 + nt * 16 + l16) * 32 + quad * 8);
    #pragma unroll
    for (int mt = 0; mt < 4; ++mt)
      #pragma unroll
      for (int nt = 0; nt < 4; ++nt)
        acc[mt][nt] = __builtin_amdgcn_mfma_f32_16x16x32_bf16(af[mt], bfv[nt], acc[mt][nt], 0, 0, 0);
    __syncthreads();
  }
  float lam = addh ? plam[0] : 0.f;
  #pragma unroll
  for (int mt = 0; mt < 4; ++mt) {
    int row = m0 + waveM * 64 + mt * 16 + quad * 4;
    #pragma unroll
    for (int nt = 0; nt < 4; ++nt) {
      int col = n0 + waveN * 64 + nt * 16 + l16;
      float b = bias ? bias[col] : 0.f;
      #pragma unroll
      for (int r = 0; r < 4; ++r) {
        size_t idx = (size_t)(row + r) * N + col;
        float v = acc[mt][nt][r] + b;
        if (add1) v += add1[idx];
        if (addh) v += lam * addh[idx];
        C[idx] = v;
      }
    }
  }
}

// ---------------- l2norm + RoPE for q,k,qb,kb --------------------------------
// proj layout: [s][5120] cols: q 0..1023, k 1024.., v 2048.., qb 3072.., kb 4096..
__global__ __launch_bounds__(256) void qkprep_k(const float* __restrict__ proj,
    __bf16* __restrict__ qo, __bf16* __restrict__ ko,
    float* __restrict__ qbo, float* __restrict__ kbo) {
  int gw = blockIdx.x * 4 + (threadIdx.x >> 6);
  int lane = threadIdx.x & 63;
  int s = gw >> 4, h = gw & 15;
  int j = lane & 31;
  float inv = powf(1000.0f, -(float)j * (1.0f / 32.0f));
  float ang = (float)s * inv;
  float cb = (float)(__bf16)cosf(ang);   // match reference bf16 tables
  float sb = (float)(__bf16)sinf(ang);
  size_t ibase = (size_t)s * 5120 + h * 64 + lane;
  size_t obase = (size_t)s * 1024 + h * 64 + lane;
  bool lo = lane < 32;

  auto proc = [&](const float* src) -> float {
    float xv = src[ibase];
    float ss = xv * xv;
    #pragma unroll
    for (int o = 32; o > 0; o >>= 1) ss += __shfl_xor(ss, o);
    float y = xv / fmaxf(sqrtf(ss), 1e-12f);
    float yp = __shfl_xor(y, 32);
    return lo ? (y * cb + yp * sb) : (y * cb - yp * sb);
  };
  qo[obase]  = (__bf16)proc(proj + 0);
  ko[obase]  = (__bf16)proc(proj + 1024);
  qbo[obase] = proc(proj + 3072);
  kbo[obase] = proc(proj + 4096);
}

// ---------------- sb row-sum via cumsum: sb[s][h] = 0.125 * qb_s . cumsum(kb)_s
__global__ __launch_bounds__(64) void sbrow_k(const float* __restrict__ qb,
                                              const float* __restrict__ kb,
                                              float* __restrict__ sb) {
  int h = blockIdx.x, d = threadIdx.x;
  size_t base = (size_t)h * 64 + d;
  float run = 0.f;
  for (int s0 = 0; s0 < 2048; s0 += 4) {
    float p[4];
    #pragma unroll
    for (int u = 0; u < 4; ++u) {
      size_t off = (size_t)(s0 + u) * 1024 + base;
      run += kb[off];
      p[u] = qb[off] * run;
    }
    #pragma unroll
    for (int o = 32; o > 0; o >>= 1) {
      #pragma unroll
      for (int u = 0; u < 4; ++u) p[u] += __shfl_xor(p[u], o);
    }
    if (d == 0) {
      #pragma unroll
      for (int u = 0; u < 4; ++u) sb[(s0 + u) * 16 + h] = 0.125f * p[u];
    }
  }
}

// ---------------- flash attention: per (q-tile 128, head), BN=64 key tiles --
// y[s][h*64+d] = l2s * softmax(q k^T, causal) v + sbrow[s][h]
__global__ __launch_bounds__(256) void attn_k(const __bf16* __restrict__ qg,
    const __bf16* __restrict__ kg, const __bf16* __restrict__ vtg,
    const float* __restrict__ sbr, const float* __restrict__ pl2s,
    __bf16* __restrict__ yo) {
  __shared__ __bf16 sU[128 * 64];   // sK (64x64, load/S phase) then sP (128x64)
  __shared__ __bf16 sVt[64 * 64];   // [d][key]
  __shared__ float  sS[128 * 64];
  __shared__ float  mrow[128], lrow[128], arow[128];
  const int qt = blockIdx.x, hh = blockIdx.y;
  const int tid = threadIdx.x, lane = tid & 63, wave = tid >> 6;
  const int quad = lane >> 4, l16 = lane & 15;
  const int waveRow = wave * 32;
  if (tid < 128) { mrow[tid] = -INFINITY; lrow[tid] = 0.f; }
  // Q fragments in registers (rows waveRow..+31)
  bf16x8 qf[2][2];
  #pragma unroll
  for (int mt = 0; mt < 2; ++mt)
    #pragma unroll
    for (int kk = 0; kk < 2; ++kk)
      qf[mt][kk] = *(const bf16x8*)(qg +
          (size_t)(qt * 128 + waveRow + mt * 16 + l16) * 1024 + hh * 64 + kk * 32 + quad * 8);
  f32x4 accO[2][4] = {};
  const int ktmax = 2 * qt + 1;
  for (int kt = 0; kt <= ktmax; ++kt) {
    for (int c = tid; c < 512; c += 256) {
      int r = c >> 3, dg = (c & 7) * 8;
      *(uint4*)(sU + r * 64 + dg)  = *(const uint4*)(kg + (size_t)(kt * 64 + r) * 1024 + hh * 64 + dg);
      *(uint4*)(sVt + r * 64 + dg) = *(const uint4*)(vtg + (size_t)(hh * 64 + r) * 2048 + kt * 64 + dg);
    }
    __syncthreads();
    const bool diag = (kt >= 2 * qt);
    #pragma unroll
    for (int nt = 0; nt < 4; ++nt) {
      bf16x8 b0 = *(const bf16x8*)(sU + (nt * 16 + l16) * 64 + quad * 8);
      bf16x8 b1 = *(const bf16x8*)(sU + (nt * 16 + l16) * 64 + 32 + quad * 8);
      #pragma unroll
      for (int mt = 0; mt < 2; ++mt) {
        f32x4 sa = {0.f, 0.f, 0.f, 0.f};
        sa = __builtin_amdgcn_mfma_f32_16x16x32_bf16(qf[mt][0], b0, sa, 0, 0, 0);
        sa = __builtin_amdgcn_mfma_f32_16x16x32_bf16(qf[mt][1], b1, sa, 0, 0, 0);
        int colL = nt * 16 + l16;
        #pragma unroll
        for (int r = 0; r < 4; ++r) {
          int rowL = waveRow + mt * 16 + quad * 4 + r;
          float v = sa[r];
          if (diag && (kt * 64 + colL > qt * 128 + rowL)) v = -INFINITY;
          sS[rowL * 64 + colL] = v;
        }
      }
    }
    __syncthreads();
    {  // online softmax: 2 threads per row
      int row = tid >> 1, half = tid & 1;
      const float* sr = sS + row * 64 + half * 32;
      float mx = -INFINITY;
      for (int jj = 0; jj < 32; ++jj) mx = fmaxf(mx, sr[jj]);
      mx = fmaxf(mx, __shfl_xor(mx, 1));
      float mold = mrow[row];
      float mnew = fmaxf(mold, mx);
      float sum = 0.f;
      __bf16* pr = sU + row * 64 + half * 32;  // sP aliases sK (safe: barriers)
      for (int jj = 0; jj < 32; ++jj) {
        float p = expf(sr[jj] - mnew);
        sum += p;
        pr[jj] = (__bf16)p;
      }
      sum += __shfl_xor(sum, 1);
      if (half == 0) {
        float alpha = expf(mold - mnew);
        lrow[row] = lrow[row] * alpha + sum;
        mrow[row] = mnew;
        arow[row] = alpha;
      }
    }
    __syncthreads();
    // rescale O, then O += P V
    float al[2][4];
    #pragma unroll
    for (int mt = 0; mt < 2; ++mt)
      #pragma unroll
      for (int r = 0; r < 4; ++r)
        al[mt][r] = arow[waveRow + mt * 16 + quad * 4 + r];
    #pragma unroll
    for (int mt = 0; mt < 2; ++mt)
      #pragma unroll
      for (int nt = 0; nt < 4; ++nt)
        #pragma unroll
        for (int r = 0; r < 4; ++r)
          accO[mt][nt][r] *= al[mt][r];
    #pragma unroll
    for (int kk = 0; kk < 2; ++kk) {
      bf16x8 a0 = *(const bf16x8*)(sU + (waveRow + l16) * 64 + kk * 32 + quad * 8);
      bf16x8 a1 = *(const bf16x8*)(sU + (waveRow + 16 + l16) * 64 + kk * 32 + quad * 8);
      #pragma unroll
      for (int nt = 0; nt < 4; ++nt) {
        bf16x8 bv = *(const bf16x8*)(sVt + (nt * 16 + l16) * 64 + kk * 32 + quad * 8);
        accO[0][nt] = __builtin_amdgcn_mfma_f32_16x16x32_bf16(a0, bv, accO[0][nt], 0, 0, 0);
        accO[1][nt] = __builtin_amdgcn_mfma_f32_16x16x32_bf16(a1, bv, accO[1][nt], 0, 0, 0);
      }
    }
    __syncthreads();
  }
  float l2s = pl2s[0];
  #pragma unroll
  for (int mt = 0; mt < 2; ++mt)
    #pragma unroll
    for (int nt = 0; nt < 4; ++nt) {
      int dcol = nt * 16 + l16;
      #pragma unroll
      for (int r = 0; r < 4; ++r) {
        int rowL = waveRow + mt * 16 + quad * 4 + r;
        int sg = qt * 128 + rowL;
        float val = l2s * accO[mt][nt][r] / lrow[rowL] + sbr[sg * 16 + hh];
        yo[(size_t)sg * 1024 + hh * 64 + dcol] = (__bf16)val;
      }
    }
}

// ---------------- SwiGLU: ffin = silu(u[:,4096+i]) * u[:,i], bf16 ----------
__global__ __launch_bounds__(256) void silu_k(const float* __restrict__ u,
                                              __bf16* __restrict__ ffin) {
  int i = blockIdx.x * 256 + threadIdx.x;
  int s = i >> 10, c = (i & 1023) * 4;
  const float4 xp = *(const float4*)(u + (size_t)s * 8192 + c);
  const float4 g  = *(const float4*)(u + (size_t)s * 8192 + 4096 + c);
  __bf16* o = ffin + (size_t)s * 4096 + c;
  o[0] = (__bf16)(xp.x * g.x / (1.f + expf(-g.x)));
  o[1] = (__bf16)(xp.y * g.y / (1.f + expf(-g.y)));
  o[2] = (__bf16)(xp.z * g.z / (1.f + expf(-g.z)));
  o[3] = (__bf16)(xp.w * g.w / (1.f + expf(-g.w)));
}

extern "C" void kernel_launch(void* const* d_in, const int* in_sizes, int n_in,
                              void* d_out, int out_size, void* d_ws, size_t ws_size,
                              hipStream_t stream) {
  (void)in_sizes; (void)n_in; (void)out_size; (void)ws_size;
  const float* hs   = (const float*)d_in[0];
  const float* Wq   = (const float*)d_in[1];
  const float* Wk   = (const float*)d_in[2];
  const float* Wv   = (const float*)d_in[3];
  const float* Wqb  = (const float*)d_in[4];
  const float* Wkb  = (const float*)d_in[5];
  const float* Wo   = (const float*)d_in[6];
  const float* bo   = (const float*)d_in[7];
  const float* W1   = (const float*)d_in[8];
  const float* b1   = (const float*)d_in[9];
  const float* W2   = (const float*)d_in[10];
  const float* b2   = (const float*)d_in[11];
  const float* plam = (const float*)d_in[12];
  const float* pl2s = (const float*)d_in[13];
  float* out = (float*)d_out;
  char* ws = (char*)d_ws;

  size_t off = 0;
  auto alloc = [&](size_t bytes) { char* p = ws + off; off += (bytes + 255) & ~(size_t)255; return p; };
  __bf16* Wt5  = (__bf16*)alloc((size_t)5 * 1024 * 1024 * 2);  // q,k,v,qb,kb transposed bf16
  __bf16* Wot  = (__bf16*)alloc((size_t)1024 * 1024 * 2);
  __bf16* W1t  = (__bf16*)alloc((size_t)8192 * 1024 * 2);
  __bf16* W2t  = (__bf16*)alloc((size_t)1024 * 4096 * 2);
  __bf16* xbf  = (__bf16*)alloc((size_t)2048 * 1024 * 2);
  char* ureg = ws + off;  // u (64 MB) aliases [proj,qbf32,kbf32,qbf,kbf] (dead by FFN1)
  float*  proj  = (float*)alloc((size_t)2048 * 5120 * 4);
  float*  qbf32 = (float*)alloc((size_t)2048 * 1024 * 4);
  float*  kbf32 = (float*)alloc((size_t)2048 * 1024 * 4);
  __bf16* qbf   = (__bf16*)alloc((size_t)2048 * 1024 * 2);
  __bf16* kbf   = (__bf16*)alloc((size_t)2048 * 1024 * 2);
  float*  u     = (float*)ureg;
  __bf16* vtbf  = (__bf16*)alloc((size_t)1024 * 2048 * 2);
  __bf16* ybf   = (__bf16*)alloc((size_t)2048 * 1024 * 2);
  float*  sbrow = (float*)alloc((size_t)2048 * 16 * 4);
  float*  attn  = (float*)alloc((size_t)2048 * 1024 * 4);
  __bf16* ffin  = (__bf16*)alloc((size_t)2048 * 4096 * 2);

  // weight transpose+convert (once per launch)
  tconv_k<<<dim3(32, 32), 256, 0, stream>>>(Wq,  Wt5,               1024, 1024);
  tconv_k<<<dim3(32, 32), 256, 0, stream>>>(Wk,  Wt5 + 1048576,     1024, 1024);
  tconv_k<<<dim3(32, 32), 256, 0, stream>>>(Wv,  Wt5 + 2 * 1048576, 1024, 1024);
  tconv_k<<<dim3(32, 32), 256, 0, stream>>>(Wqb, Wt5 + 3 * 1048576, 1024, 1024);
  tconv_k<<<dim3(32, 32), 256, 0, stream>>>(Wkb, Wt5 + 4 * 1048576, 1024, 1024);
  tconv_k<<<dim3(32, 32), 256, 0, stream>>>(Wo,  Wot,               1024, 1024);
  tconv_k<<<dim3(256, 32), 256, 0, stream>>>(W1, W1t,               8192, 1024);
  tconv_k<<<dim3(32, 128), 256, 0, stream>>>(W2, W2t,               1024, 4096);

  rmsnorm_k<<<2048, 256, 0, stream>>>(hs, xbf);
  // fused 5-way projection: x @ [Wq|Wk|Wv|Wqb|Wkb]
  gemm_bt_k<<<dim3(40, 16), 256, 0, stream>>>(xbf, Wt5, proj, 5120, 1024,
                                              nullptr, nullptr, nullptr, nullptr);
  qkprep_k<<<8192, 256, 0, stream>>>(proj, qbf, kbf, qbf32, kbf32);
  // v transposed to [h*64+d][s] bf16 for PV B-operand
  tconv_k<<<dim3(32, 64), 256, 0, stream>>>(proj + 2048, vtbf, 5120, 2048);
  sbrow_k<<<16, 64, 0, stream>>>(qbf32, kbf32, sbrow);
  attn_k<<<dim3(16, 16), 256, 0, stream>>>(qbf, kbf, vtbf, sbrow, pl2s, ybf);
  // attn_out = y @ Wo + bo
  gemm_bt_k<<<dim3(8, 16), 256, 0, stream>>>(ybf, Wot, attn, 1024, 1024,
                                             bo, nullptr, nullptr, nullptr);
  // u = x @ W1 + b1
  gemm_bt_k<<<dim3(64, 16), 256, 0, stream>>>(xbf, W1t, u, 8192, 1024,
                                              b1, nullptr, nullptr, nullptr);
  silu_k<<<8192, 256, 0, stream>>>(u, ffin);
  // out = ffin @ W2 + b2 + attn_out + lambda * h
  gemm_bt_k<<<dim3(8, 16), 256, 0, stream>>>(ffin, W2t, out, 1024, 4096,
                                             b2, attn, hs, plam);
}

// Round 2
// 692.814 us; speedup vs baseline: 1.5488x; 1.5488x over previous
//
#include <hip/hip_runtime.h>
#include <hip/hip_bf16.h>
#include <math.h>

typedef __bf16 bf16x8 __attribute__((ext_vector_type(8)));
typedef float  f32x4  __attribute__((ext_vector_type(4)));

#define GLD16(g, l) __builtin_amdgcn_global_load_lds(                      \
    (const __attribute__((address_space(1))) void*)(g),                    \
    (__attribute__((address_space(3))) void*)(l), 16, 0, 0)

// ---------------- transpose + f32 -> bf16 convert (out[c][r] = in[r][c]) ----
__global__ __launch_bounds__(256) void tconv_k(const float* __restrict__ in,
                                               __bf16* __restrict__ out,
                                               int ldin, int ldout) {
  __shared__ float t[32][33];
  int c0 = blockIdx.x * 32, r0 = blockIdx.y * 32;
  int tx = threadIdx.x & 31, ty = threadIdx.x >> 5;
  #pragma unroll
  for (int i = ty; i < 32; i += 8)
    t[i][tx] = in[(size_t)(r0 + i) * ldin + c0 + tx];
  __syncthreads();
  #pragma unroll
  for (int i = ty; i < 32; i += 8)
    out[(size_t)(c0 + i) * ldout + r0 + tx] = (__bf16)t[tx][i];
}

// ---------------- RMSNorm: x = h * rsqrt(mean(h^2) + eps), bf16 out --------
__global__ __launch_bounds__(256) void rmsnorm_k(const float* __restrict__ hs,
                                                 __bf16* __restrict__ x) {
  int row = blockIdx.x, tid = threadIdx.x;
  const float4 v = ((const float4*)(hs + (size_t)row * 1024))[tid];
  float ss = v.x * v.x + v.y * v.y + v.z * v.z + v.w * v.w;
  #pragma unroll
  for (int o = 32; o > 0; o >>= 1) ss += __shfl_xor(ss, o);
  __shared__ float ps[4];
  if ((tid & 63) == 0) ps[tid >> 6] = ss;
  __syncthreads();
  float tot = ps[0] + ps[1] + ps[2] + ps[3];
  float r = rsqrtf(tot * (1.0f / 1024.0f) + 1.1920929e-7f);
  __bf16* xr = x + (size_t)row * 1024 + tid * 4;
  xr[0] = (__bf16)(v.x * r); xr[1] = (__bf16)(v.y * r);
  xr[2] = (__bf16)(v.z * r); xr[3] = (__bf16)(v.w * r);
}

// ---------------- GEMM: C(MxN,f32) = A(MxK,bf16) * Bt(NxK,bf16)^T ----------
// m97 structure: 128x128 tile, 4 waves, 16x16x32 bf16 MFMA, global_load_lds.
// Optional epilogue: +bias[col], +add1[idx], +lam*addh[idx]
__global__ __launch_bounds__(256) void gemm_bt_k(
    const __bf16* __restrict__ A, const __bf16* __restrict__ Bt,
    float* __restrict__ C, int N, int K,
    const float* __restrict__ bias, const float* __restrict__ add1,
    const float* __restrict__ addh, const float* __restrict__ plam) {
  __shared__ __bf16 sA[128 * 32];
  __shared__ __bf16 sB[128 * 32];
  const int tid = threadIdx.x;
  const int lane = tid & 63;
  const int quad = lane >> 4, l16 = lane & 15;
  const int wave = tid >> 6;
  const int waveM = wave >> 1, waveN = wave & 1;
  const int m0 = blockIdx.y * 128, n0 = blockIdx.x * 128;
  const int rowS = tid >> 2;
  const int kgS = (tid & 3) * 8;
  const __bf16* gA0 = A + (size_t)(m0 + rowS) * K + kgS;
  const __bf16* gA1 = gA0 + (size_t)64 * K;
  const __bf16* gB0 = Bt + (size_t)(n0 + rowS) * K + kgS;
  const __bf16* gB1 = gB0 + (size_t)64 * K;
  __bf16* lA0 = sA + tid * 8; __bf16* lA1 = sA + 2048 + tid * 8;
  __bf16* lB0 = sB + tid * 8; __bf16* lB1 = sB + 2048 + tid * 8;
  f32x4 acc[4][4] = {};
  for (int k0 = 0; k0 < K; k0 += 32) {
    GLD16(gA0 + k0, lA0);
    GLD16(gA1 + k0, lA1);
    GLD16(gB0 + k0, lB0);
    GLD16(gB1 + k0, lB1);
    __syncthreads();
    bf16x8 af[4], bfv[4];
    #pragma unroll
    for (int mt = 0; mt < 4; ++mt)
      af[mt] = *(const bf16x8*)(sA + (waveM * 64 + mt * 16 + l16) * 32 + quad * 8);
    #pragma unroll
    for (int nt = 0; nt < 4; ++nt)
      bfv[nt] = *(const bf16x8*)(sB + (waveN * 64 + nt * 16 + l16) * 32 + quad * 8);
    #pragma unroll
    for (int mt = 0; mt < 4; ++mt)
      #pragma unroll
      for (int nt = 0; nt < 4; ++nt)
        acc[mt][nt] = __builtin_amdgcn_mfma_f32_16x16x32_bf16(af[mt], bfv[nt], acc[mt][nt], 0, 0, 0);
    __syncthreads();
  }
  float lam = addh ? plam[0] : 0.f;
  #pragma unroll
  for (int mt = 0; mt < 4; ++mt) {
    int row = m0 + waveM * 64 + mt * 16 + quad * 4;
    #pragma unroll
    for (int nt = 0; nt < 4; ++nt) {
      int col = n0 + waveN * 64 + nt * 16 + l16;
      float b = bias ? bias[col] : 0.f;
      #pragma unroll
      for (int r = 0; r < 4; ++r) {
        size_t idx = (size_t)(row + r) * N + col;
        float v = acc[mt][nt][r] + b;
        if (add1) v += add1[idx];
        if (addh) v += lam * addh[idx];
        C[idx] = v;
      }
    }
  }
}

// ---------------- l2norm + RoPE for q,k,qb,kb --------------------------------
// proj layout: [s][5120] cols: q 0..1023, k 1024.., v 2048.., qb 3072.., kb 4096..
__global__ __launch_bounds__(256) void qkprep_k(const float* __restrict__ proj,
    __bf16* __restrict__ qo, __bf16* __restrict__ ko,
    float* __restrict__ qbo, float* __restrict__ kbo) {
  int gw = blockIdx.x * 4 + (threadIdx.x >> 6);
  int lane = threadIdx.x & 63;
  int s = gw >> 4, h = gw & 15;
  int j = lane & 31;
  float inv = powf(1000.0f, -(float)j * (1.0f / 32.0f));
  float ang = (float)s * inv;
  float cb = (float)(__bf16)cosf(ang);   // match reference bf16 tables
  float sb = (float)(__bf16)sinf(ang);
  size_t ibase = (size_t)s * 5120 + h * 64 + lane;
  size_t obase = (size_t)s * 1024 + h * 64 + lane;
  bool lo = lane < 32;

  auto proc = [&](const float* src) -> float {
    float xv = src[ibase];
    float ss = xv * xv;
    #pragma unroll
    for (int o = 32; o > 0; o >>= 1) ss += __shfl_xor(ss, o);
    float y = xv / fmaxf(sqrtf(ss), 1e-12f);
    float yp = __shfl_xor(y, 32);
    return lo ? (y * cb + yp * sb) : (y * cb - yp * sb);
  };
  qo[obase]  = (__bf16)proc(proj + 0);
  ko[obase]  = (__bf16)proc(proj + 1024);
  qbo[obase] = proc(proj + 3072);
  kbo[obase] = proc(proj + 4096);
}

// ---------------- sb row-sum via two-level cumsum ---------------------------
// sb[s][h] = 0.125 * qb_s . cumsum(kb)_s   decomposed into 32-row tiles.
// kbsum_k: tsum[t][h][d] = sum of kb rows t*32..t*32+31
__global__ __launch_bounds__(64) void kbsum_k(const float* __restrict__ kb,
                                              float* __restrict__ tsum) {
  int t = blockIdx.x, h = blockIdx.y, d = threadIdx.x;
  size_t base = (size_t)h * 64 + d;
  float s = 0.f;
  #pragma unroll 4
  for (int r = 0; r < 32; ++r)
    s += kb[(size_t)(t * 32 + r) * 1024 + base];
  tsum[(t * 16 + h) * 64 + d] = s;
}

// sbrow2_k: block (t,h): prefix from tile sums, then 32 serial rows.
__global__ __launch_bounds__(64) void sbrow2_k(const float* __restrict__ qb,
                                               const float* __restrict__ kb,
                                               const float* __restrict__ tsum,
                                               float* __restrict__ sb) {
  int t = blockIdx.x, h = blockIdx.y, d = threadIdx.x;
  size_t base = (size_t)h * 64 + d;
  float run = 0.f;
  for (int tp = 0; tp < t; ++tp) run += tsum[(tp * 16 + h) * 64 + d];
  for (int s0 = 0; s0 < 32; s0 += 4) {
    float p[4];
    #pragma unroll
    for (int u = 0; u < 4; ++u) {
      size_t off = (size_t)(t * 32 + s0 + u) * 1024 + base;
      run += kb[off];
      p[u] = qb[off] * run;
    }
    #pragma unroll
    for (int o = 32; o > 0; o >>= 1) {
      #pragma unroll
      for (int u = 0; u < 4; ++u) p[u] += __shfl_xor(p[u], o);
    }
    if (d == 0) {
      #pragma unroll
      for (int u = 0; u < 4; ++u) sb[(t * 32 + s0 + u) * 16 + h] = 0.125f * p[u];
    }
  }
}

// ---------------- flash attention: per (q-tile 128, head), BN=64 key tiles --
// y[s][h*64+d] = l2s * softmax(q k^T, causal) v + sbrow[s][h]
__global__ __launch_bounds__(256) void attn_k(const __bf16* __restrict__ qg,
    const __bf16* __restrict__ kg, const __bf16* __restrict__ vtg,
    const float* __restrict__ sbr, const float* __restrict__ pl2s,
    __bf16* __restrict__ yo) {
  __shared__ __bf16 sU[128 * 64];   // sK (64x64, load/S phase) then sP (128x64)
  __shared__ __bf16 sVt[64 * 64];   // [d][key]
  __shared__ float  sS[128 * 64];
  __shared__ float  mrow[128], lrow[128], arow[128];
  const int qt = blockIdx.x, hh = blockIdx.y;
  const int tid = threadIdx.x, lane = tid & 63, wave = tid >> 6;
  const int quad = lane >> 4, l16 = lane & 15;
  const int waveRow = wave * 32;
  if (tid < 128) { mrow[tid] = -INFINITY; lrow[tid] = 0.f; }
  // Q fragments in registers (rows waveRow..+31)
  bf16x8 qf[2][2];
  #pragma unroll
  for (int mt = 0; mt < 2; ++mt)
    #pragma unroll
    for (int kk = 0; kk < 2; ++kk)
      qf[mt][kk] = *(const bf16x8*)(qg +
          (size_t)(qt * 128 + waveRow + mt * 16 + l16) * 1024 + hh * 64 + kk * 32 + quad * 8);
  f32x4 accO[2][4] = {};
  const int ktmax = 2 * qt + 1;
  for (int kt = 0; kt <= ktmax; ++kt) {
    for (int c = tid; c < 512; c += 256) {
      int r = c >> 3, dg = (c & 7) * 8;
      *(uint4*)(sU + r * 64 + dg)  = *(const uint4*)(kg + (size_t)(kt * 64 + r) * 1024 + hh * 64 + dg);
      *(uint4*)(sVt + r * 64 + dg) = *(const uint4*)(vtg + (size_t)(hh * 64 + r) * 2048 + kt * 64 + dg);
    }
    __syncthreads();
    const bool diag = (kt >= 2 * qt);
    #pragma unroll
    for (int nt = 0; nt < 4; ++nt) {
      bf16x8 b0 = *(const bf16x8*)(sU + (nt * 16 + l16) * 64 + quad * 8);
      bf16x8 b1 = *(const bf16x8*)(sU + (nt * 16 + l16) * 64 + 32 + quad * 8);
      #pragma unroll
      for (int mt = 0; mt < 2; ++mt) {
        f32x4 sa = {0.f, 0.f, 0.f, 0.f};
        sa = __builtin_amdgcn_mfma_f32_16x16x32_bf16(qf[mt][0], b0, sa, 0, 0, 0);
        sa = __builtin_amdgcn_mfma_f32_16x16x32_bf16(qf[mt][1], b1, sa, 0, 0, 0);
        int colL = nt * 16 + l16;
        #pragma unroll
        for (int r = 0; r < 4; ++r) {
          int rowL = waveRow + mt * 16 + quad * 4 + r;
          float v = sa[r];
          if (diag && (kt * 64 + colL > qt * 128 + rowL)) v = -INFINITY;
          sS[rowL * 64 + colL] = v;
        }
      }
    }
    __syncthreads();
    {  // online softmax: 2 threads per row
      int row = tid >> 1, half = tid & 1;
      const float* sr = sS + row * 64 + half * 32;
      float mx = -INFINITY;
      for (int jj = 0; jj < 32; ++jj) mx = fmaxf(mx, sr[jj]);
      mx = fmaxf(mx, __shfl_xor(mx, 1));
      float mold = mrow[row];
      float mnew = fmaxf(mold, mx);
      float sum = 0.f;
      __bf16* pr = sU + row * 64 + half * 32;  // sP aliases sK (safe: barriers)
      for (int jj = 0; jj < 32; ++jj) {
        float p = expf(sr[jj] - mnew);
        sum += p;
        pr[jj] = (__bf16)p;
      }
      sum += __shfl_xor(sum, 1);
      if (half == 0) {
        float alpha = expf(mold - mnew);
        lrow[row] = lrow[row] * alpha + sum;
        mrow[row] = mnew;
        arow[row] = alpha;
      }
    }
    __syncthreads();
    // rescale O, then O += P V
    float al[2][4];
    #pragma unroll
    for (int mt = 0; mt < 2; ++mt)
      #pragma unroll
      for (int r = 0; r < 4; ++r)
        al[mt][r] = arow[waveRow + mt * 16 + quad * 4 + r];
    #pragma unroll
    for (int mt = 0; mt < 2; ++mt)
      #pragma unroll
      for (int nt = 0; nt < 4; ++nt)
        #pragma unroll
        for (int r = 0; r < 4; ++r)
          accO[mt][nt][r] *= al[mt][r];
    #pragma unroll
    for (int kk = 0; kk < 2; ++kk) {
      bf16x8 a0 = *(const bf16x8*)(sU + (waveRow + l16) * 64 + kk * 32 + quad * 8);
      bf16x8 a1 = *(const bf16x8*)(sU + (waveRow + 16 + l16) * 64 + kk * 32 + quad * 8);
      #pragma unroll
      for (int nt = 0; nt < 4; ++nt) {
        bf16x8 bv = *(const bf16x8*)(sVt + (nt * 16 + l16) * 64 + kk * 32 + quad * 8);
        accO[0][nt] = __builtin_amdgcn_mfma_f32_16x16x32_bf16(a0, bv, accO[0][nt], 0, 0, 0);
        accO[1][nt] = __builtin_amdgcn_mfma_f32_16x16x32_bf16(a1, bv, accO[1][nt], 0, 0, 0);
      }
    }
    __syncthreads();
  }
  float l2s = pl2s[0];
  #pragma unroll
  for (int mt = 0; mt < 2; ++mt)
    #pragma unroll
    for (int nt = 0; nt < 4; ++nt) {
      int dcol = nt * 16 + l16;
      #pragma unroll
      for (int r = 0; r < 4; ++r) {
        int rowL = waveRow + mt * 16 + quad * 4 + r;
        int sg = qt * 128 + rowL;
        float val = l2s * accO[mt][nt][r] / lrow[rowL] + sbr[sg * 16 + hh];
        yo[(size_t)sg * 1024 + hh * 64 + dcol] = (__bf16)val;
      }
    }
}

// ---------------- SwiGLU: ffin = silu(u[:,4096+i]) * u[:,i], bf16 ----------
__global__ __launch_bounds__(256) void silu_k(const float* __restrict__ u,
                                              __bf16* __restrict__ ffin) {
  int i = blockIdx.x * 256 + threadIdx.x;
  int s = i >> 10, c = (i & 1023) * 4;
  const float4 xp = *(const float4*)(u + (size_t)s * 8192 + c);
  const float4 g  = *(const float4*)(u + (size_t)s * 8192 + 4096 + c);
  __bf16* o = ffin + (size_t)s * 4096 + c;
  o[0] = (__bf16)(xp.x * g.x / (1.f + expf(-g.x)));
  o[1] = (__bf16)(xp.y * g.y / (1.f + expf(-g.y)));
  o[2] = (__bf16)(xp.z * g.z / (1.f + expf(-g.z)));
  o[3] = (__bf16)(xp.w * g.w / (1.f + expf(-g.w)));
}

extern "C" void kernel_launch(void* const* d_in, const int* in_sizes, int n_in,
                              void* d_out, int out_size, void* d_ws, size_t ws_size,
                              hipStream_t stream) {
  (void)in_sizes; (void)n_in; (void)out_size; (void)ws_size;
  const float* hs   = (const float*)d_in[0];
  const float* Wq   = (const float*)d_in[1];
  const float* Wk   = (const float*)d_in[2];
  const float* Wv   = (const float*)d_in[3];
  const float* Wqb  = (const float*)d_in[4];
  const float* Wkb  = (const float*)d_in[5];
  const float* Wo   = (const float*)d_in[6];
  const float* bo   = (const float*)d_in[7];
  const float* W1   = (const float*)d_in[8];
  const float* b1   = (const float*)d_in[9];
  const float* W2   = (const float*)d_in[10];
  const float* b2   = (const float*)d_in[11];
  const float* plam = (const float*)d_in[12];
  const float* pl2s = (const float*)d_in[13];
  float* out = (float*)d_out;
  char* ws = (char*)d_ws;

  size_t off = 0;
  auto alloc = [&](size_t bytes) { char* p = ws + off; off += (bytes + 255) & ~(size_t)255; return p; };
  __bf16* Wt5  = (__bf16*)alloc((size_t)5 * 1024 * 1024 * 2);  // q,k,v,qb,kb transposed bf16
  __bf16* Wot  = (__bf16*)alloc((size_t)1024 * 1024 * 2);
  __bf16* W1t  = (__bf16*)alloc((size_t)8192 * 1024 * 2);
  __bf16* W2t  = (__bf16*)alloc((size_t)1024 * 4096 * 2);
  __bf16* xbf  = (__bf16*)alloc((size_t)2048 * 1024 * 2);
  char* ureg = ws + off;  // u (64 MB) aliases [proj,qbf32,kbf32,qbf,kbf] (dead by FFN1)
  float*  proj  = (float*)alloc((size_t)2048 * 5120 * 4);
  float*  qbf32 = (float*)alloc((size_t)2048 * 1024 * 4);
  float*  kbf32 = (float*)alloc((size_t)2048 * 1024 * 4);
  __bf16* qbf   = (__bf16*)alloc((size_t)2048 * 1024 * 2);
  __bf16* kbf   = (__bf16*)alloc((size_t)2048 * 1024 * 2);
  float*  u     = (float*)ureg;
  __bf16* vtbf  = (__bf16*)alloc((size_t)1024 * 2048 * 2);
  __bf16* ybf   = (__bf16*)alloc((size_t)2048 * 1024 * 2);
  float*  sbrow = (float*)alloc((size_t)2048 * 16 * 4);
  float*  tsum  = (float*)alloc((size_t)64 * 16 * 64 * 4);
  float*  attn  = (float*)alloc((size_t)2048 * 1024 * 4);
  __bf16* ffin  = (__bf16*)alloc((size_t)2048 * 4096 * 2);

  // weight transpose+convert (once per launch)
  tconv_k<<<dim3(32, 32), 256, 0, stream>>>(Wq,  Wt5,               1024, 1024);
  tconv_k<<<dim3(32, 32), 256, 0, stream>>>(Wk,  Wt5 + 1048576,     1024, 1024);
  tconv_k<<<dim3(32, 32), 256, 0, stream>>>(Wv,  Wt5 + 2 * 1048576, 1024, 1024);
  tconv_k<<<dim3(32, 32), 256, 0, stream>>>(Wqb, Wt5 + 3 * 1048576, 1024, 1024);
  tconv_k<<<dim3(32, 32), 256, 0, stream>>>(Wkb, Wt5 + 4 * 1048576, 1024, 1024);
  tconv_k<<<dim3(32, 32), 256, 0, stream>>>(Wo,  Wot,               1024, 1024);
  tconv_k<<<dim3(256, 32), 256, 0, stream>>>(W1, W1t,               8192, 1024);
  tconv_k<<<dim3(32, 128), 256, 0, stream>>>(W2, W2t,               1024, 4096);

  rmsnorm_k<<<2048, 256, 0, stream>>>(hs, xbf);
  // fused 5-way projection: x @ [Wq|Wk|Wv|Wqb|Wkb]
  gemm_bt_k<<<dim3(40, 16), 256, 0, stream>>>(xbf, Wt5, proj, 5120, 1024,
                                              nullptr, nullptr, nullptr, nullptr);
  qkprep_k<<<8192, 256, 0, stream>>>(proj, qbf, kbf, qbf32, kbf32);
  // v transposed to [h*64+d][s] bf16 for PV B-operand
  tconv_k<<<dim3(32, 64), 256, 0, stream>>>(proj + 2048, vtbf, 5120, 2048);
  kbsum_k<<<dim3(64, 16), 64, 0, stream>>>(kbf32, tsum);
  sbrow2_k<<<dim3(64, 16), 64, 0, stream>>>(qbf32, kbf32, tsum, sbrow);
  attn_k<<<dim3(16, 16), 256, 0, stream>>>(qbf, kbf, vtbf, sbrow, pl2s, ybf);
  // attn_out = y @ Wo + bo
  gemm_bt_k<<<dim3(8, 16), 256, 0, stream>>>(ybf, Wot, attn, 1024, 1024,
                                             bo, nullptr, nullptr, nullptr);
  // u = x @ W1 + b1
  gemm_bt_k<<<dim3(64, 16), 256, 0, stream>>>(xbf, W1t, u, 8192, 1024,
                                              b1, nullptr, nullptr, nullptr);
  silu_k<<<8192, 256, 0, stream>>>(u, ffin);
  // out = ffin @ W2 + b2 + attn_out + lambda * h
  gemm_bt_k<<<dim3(8, 16), 256, 0, stream>>>(ffin, W2t, out, 1024, 4096,
                                             b2, attn, hs, plam);
}

// Round 3
// 492.888 us; speedup vs baseline: 2.1770x; 1.4056x over previous
//
#include <hip/hip_runtime.h>
#include <hip/hip_bf16.h>
#include <math.h>

typedef __bf16 bf16x8 __attribute__((ext_vector_type(8)));
typedef float  f32x4  __attribute__((ext_vector_type(4)));

#define GLD16(g, l) __builtin_amdgcn_global_load_lds(                      \
    (const __attribute__((address_space(1))) void*)(g),                    \
    (__attribute__((address_space(3))) void*)(l), 16, 0, 0)

// ---------------- transpose + f32 -> bf16 convert (out[c][r] = in[r][c]) ----
__global__ __launch_bounds__(256) void tconv_k(const float* __restrict__ in,
                                               __bf16* __restrict__ out,
                                               int ldin, int ldout) {
  __shared__ float t[32][33];
  int c0 = blockIdx.x * 32, r0 = blockIdx.y * 32;
  int tx = threadIdx.x & 31, ty = threadIdx.x >> 5;
  #pragma unroll
  for (int i = ty; i < 32; i += 8)
    t[i][tx] = in[(size_t)(r0 + i) * ldin + c0 + tx];
  __syncthreads();
  #pragma unroll
  for (int i = ty; i < 32; i += 8)
    out[(size_t)(c0 + i) * ldout + r0 + tx] = (__bf16)t[tx][i];
}

// ---------------- RMSNorm: x = h * rsqrt(mean(h^2) + eps), bf16 out --------
__global__ __launch_bounds__(256) void rmsnorm_k(const float* __restrict__ hs,
                                                 __bf16* __restrict__ x) {
  int row = blockIdx.x, tid = threadIdx.x;
  const float4 v = ((const float4*)(hs + (size_t)row * 1024))[tid];
  float ss = v.x * v.x + v.y * v.y + v.z * v.z + v.w * v.w;
  #pragma unroll
  for (int o = 32; o > 0; o >>= 1) ss += __shfl_xor(ss, o);
  __shared__ float ps[4];
  if ((tid & 63) == 0) ps[tid >> 6] = ss;
  __syncthreads();
  float tot = ps[0] + ps[1] + ps[2] + ps[3];
  float r = rsqrtf(tot * (1.0f / 1024.0f) + 1.1920929e-7f);
  __bf16* xr = x + (size_t)row * 1024 + tid * 4;
  xr[0] = (__bf16)(v.x * r); xr[1] = (__bf16)(v.y * r);
  xr[2] = (__bf16)(v.z * r); xr[3] = (__bf16)(v.w * r);
}

// ---------------- GEMM 128x128: C = A * Bt^T (+bias,+add1,+lam*addh) -------
__global__ __launch_bounds__(256) void gemm_bt_k(
    const __bf16* __restrict__ A, const __bf16* __restrict__ Bt,
    float* __restrict__ C, int N, int K,
    const float* __restrict__ bias, const float* __restrict__ add1,
    const float* __restrict__ addh, const float* __restrict__ plam) {
  __shared__ __bf16 sA[128 * 32];
  __shared__ __bf16 sB[128 * 32];
  const int tid = threadIdx.x;
  const int lane = tid & 63;
  const int quad = lane >> 4, l16 = lane & 15;
  const int wave = tid >> 6;
  const int waveM = wave >> 1, waveN = wave & 1;
  const int m0 = blockIdx.y * 128, n0 = blockIdx.x * 128;
  const int rowS = tid >> 2;
  const int kgS = (tid & 3) * 8;
  const __bf16* gA0 = A + (size_t)(m0 + rowS) * K + kgS;
  const __bf16* gA1 = gA0 + (size_t)64 * K;
  const __bf16* gB0 = Bt + (size_t)(n0 + rowS) * K + kgS;
  const __bf16* gB1 = gB0 + (size_t)64 * K;
  __bf16* lA0 = sA + tid * 8; __bf16* lA1 = sA + 2048 + tid * 8;
  __bf16* lB0 = sB + tid * 8; __bf16* lB1 = sB + 2048 + tid * 8;
  f32x4 acc[4][4] = {};
  for (int k0 = 0; k0 < K; k0 += 32) {
    GLD16(gA0 + k0, lA0);
    GLD16(gA1 + k0, lA1);
    GLD16(gB0 + k0, lB0);
    GLD16(gB1 + k0, lB1);
    __syncthreads();
    bf16x8 af[4], bfv[4];
    #pragma unroll
    for (int mt = 0; mt < 4; ++mt)
      af[mt] = *(const bf16x8*)(sA + (waveM * 64 + mt * 16 + l16) * 32 + quad * 8);
    #pragma unroll
    for (int nt = 0; nt < 4; ++nt)
      bfv[nt] = *(const bf16x8*)(sB + (waveN * 64 + nt * 16 + l16) * 32 + quad * 8);
    #pragma unroll
    for (int mt = 0; mt < 4; ++mt)
      #pragma unroll
      for (int nt = 0; nt < 4; ++nt)
        acc[mt][nt] = __builtin_amdgcn_mfma_f32_16x16x32_bf16(af[mt], bfv[nt], acc[mt][nt], 0, 0, 0);
    __syncthreads();
  }
  float lam = addh ? plam[0] : 0.f;
  #pragma unroll
  for (int mt = 0; mt < 4; ++mt) {
    int row = m0 + waveM * 64 + mt * 16 + quad * 4;
    #pragma unroll
    for (int nt = 0; nt < 4; ++nt) {
      int col = n0 + waveN * 64 + nt * 16 + l16;
      float b = bias ? bias[col] : 0.f;
      #pragma unroll
      for (int r = 0; r < 4; ++r) {
        size_t idx = (size_t)(row + r) * N + col;
        float v = acc[mt][nt][r] + b;
        if (add1) v += add1[idx];
        if (addh) v += lam * addh[idx];
        C[idx] = v;
      }
    }
  }
}

// ---------------- GEMM 128x64 tile (2x block count for skinny-N GEMMs) ------
__global__ __launch_bounds__(256) void gemm_bt64_k(
    const __bf16* __restrict__ A, const __bf16* __restrict__ Bt,
    float* __restrict__ C, int N, int K,
    const float* __restrict__ bias, const float* __restrict__ add1,
    const float* __restrict__ addh, const float* __restrict__ plam) {
  __shared__ __bf16 sA[128 * 32];
  __shared__ __bf16 sB[64 * 32];
  const int tid = threadIdx.x;
  const int lane = tid & 63;
  const int quad = lane >> 4, l16 = lane & 15;
  const int wave = tid >> 6;
  const int m0 = blockIdx.y * 128, n0 = blockIdx.x * 64;
  const int rowS = tid >> 2;
  const int kgS = (tid & 3) * 8;
  const __bf16* gA0 = A + (size_t)(m0 + rowS) * K + kgS;
  const __bf16* gA1 = gA0 + (size_t)64 * K;
  const __bf16* gB0 = Bt + (size_t)(n0 + rowS) * K + kgS;
  __bf16* lA0 = sA + tid * 8; __bf16* lA1 = sA + 2048 + tid * 8;
  __bf16* lB0 = sB + tid * 8;
  f32x4 acc[2][4] = {};
  for (int k0 = 0; k0 < K; k0 += 32) {
    GLD16(gA0 + k0, lA0);
    GLD16(gA1 + k0, lA1);
    GLD16(gB0 + k0, lB0);
    __syncthreads();
    bf16x8 af[2], bfv[4];
    #pragma unroll
    for (int mt = 0; mt < 2; ++mt)
      af[mt] = *(const bf16x8*)(sA + (wave * 32 + mt * 16 + l16) * 32 + quad * 8);
    #pragma unroll
    for (int nt = 0; nt < 4; ++nt)
      bfv[nt] = *(const bf16x8*)(sB + (nt * 16 + l16) * 32 + quad * 8);
    #pragma unroll
    for (int mt = 0; mt < 2; ++mt)
      #pragma unroll
      for (int nt = 0; nt < 4; ++nt)
        acc[mt][nt] = __builtin_amdgcn_mfma_f32_16x16x32_bf16(af[mt], bfv[nt], acc[mt][nt], 0, 0, 0);
    __syncthreads();
  }
  float lam = addh ? plam[0] : 0.f;
  #pragma unroll
  for (int mt = 0; mt < 2; ++mt) {
    int row = m0 + wave * 32 + mt * 16 + quad * 4;
    #pragma unroll
    for (int nt = 0; nt < 4; ++nt) {
      int col = n0 + nt * 16 + l16;
      float b = bias ? bias[col] : 0.f;
      #pragma unroll
      for (int r = 0; r < 4; ++r) {
        size_t idx = (size_t)(row + r) * N + col;
        float v = acc[mt][nt][r] + b;
        if (add1) v += add1[idx];
        if (addh) v += lam * addh[idx];
        C[idx] = v;
      }
    }
  }
}

// ---------------- l2norm + RoPE for q,k,qb,kb --------------------------------
__global__ __launch_bounds__(256) void qkprep_k(const float* __restrict__ proj,
    __bf16* __restrict__ qo, __bf16* __restrict__ ko,
    float* __restrict__ qbo, float* __restrict__ kbo) {
  int gw = blockIdx.x * 4 + (threadIdx.x >> 6);
  int lane = threadIdx.x & 63;
  int s = gw >> 4, h = gw & 15;
  int j = lane & 31;
  float inv = powf(1000.0f, -(float)j * (1.0f / 32.0f));
  float ang = (float)s * inv;
  float cb = (float)(__bf16)cosf(ang);
  float sb = (float)(__bf16)sinf(ang);
  size_t ibase = (size_t)s * 5120 + h * 64 + lane;
  size_t obase = (size_t)s * 1024 + h * 64 + lane;
  bool lo = lane < 32;

  auto proc = [&](const float* src) -> float {
    float xv = src[ibase];
    float ss = xv * xv;
    #pragma unroll
    for (int o = 32; o > 0; o >>= 1) ss += __shfl_xor(ss, o);
    float y = xv / fmaxf(sqrtf(ss), 1e-12f);
    float yp = __shfl_xor(y, 32);
    return lo ? (y * cb + yp * sb) : (y * cb - yp * sb);
  };
  qo[obase]  = (__bf16)proc(proj + 0);
  ko[obase]  = (__bf16)proc(proj + 1024);
  qbo[obase] = proc(proj + 3072);
  kbo[obase] = proc(proj + 4096);
}

// ---------------- sb row-sum via two-level cumsum ---------------------------
__global__ __launch_bounds__(64) void kbsum_k(const float* __restrict__ kb,
                                              float* __restrict__ tsum) {
  int t = blockIdx.x, h = blockIdx.y, d = threadIdx.x;
  size_t base = (size_t)h * 64 + d;
  float s = 0.f;
  #pragma unroll 4
  for (int r = 0; r < 32; ++r)
    s += kb[(size_t)(t * 32 + r) * 1024 + base];
  tsum[(t * 16 + h) * 64 + d] = s;
}

__global__ __launch_bounds__(64) void sbrow2_k(const float* __restrict__ qb,
                                               const float* __restrict__ kb,
                                               const float* __restrict__ tsum,
                                               float* __restrict__ sb) {
  int t = blockIdx.x, h = blockIdx.y, d = threadIdx.x;
  size_t base = (size_t)h * 64 + d;
  float run = 0.f;
  for (int tp = 0; tp < t; ++tp) run += tsum[(tp * 16 + h) * 64 + d];
  for (int s0 = 0; s0 < 32; s0 += 4) {
    float p[4];
    #pragma unroll
    for (int u = 0; u < 4; ++u) {
      size_t off = (size_t)(t * 32 + s0 + u) * 1024 + base;
      run += kb[off];
      p[u] = qb[off] * run;
    }
    #pragma unroll
    for (int o = 32; o > 0; o >>= 1) {
      #pragma unroll
      for (int u = 0; u < 4; ++u) p[u] += __shfl_xor(p[u], o);
    }
    if (d == 0) {
      #pragma unroll
      for (int u = 0; u < 4; ++u) sb[(t * 32 + s0 + u) * 16 + h] = 0.125f * p[u];
    }
  }
}

// ---------------- flash attention v2: register softmax, balanced pairing ----
// Block (pair, head): processes 64-row q-tiles `pair` and `31-pair` -> every
// block does exactly 33 kt-iters. Wave w owns 16 q-rows. Softmax entirely in
// registers (row = (quad,reg) -> shfl_xor over l16 lanes). P transposed via
// per-wave-private LDS region, stride 72 bf16 (144B rows, 16B-aligned).
__global__ __launch_bounds__(256) void attn_k(const __bf16* __restrict__ qg,
    const __bf16* __restrict__ kg, const __bf16* __restrict__ vtg,
    const float* __restrict__ sbr, const float* __restrict__ pl2s,
    __bf16* __restrict__ yo) {
  __shared__ __bf16 sK[64 * 64];
  __shared__ __bf16 sVt[64 * 64];
  __shared__ __bf16 sP[64 * 72];
  const int pair = blockIdx.x, hh = blockIdx.y;
  const int tid = threadIdx.x, lane = tid & 63, w = tid >> 6;
  const int quad = lane >> 4, l16 = lane & 15;
  const float l2s = pl2s[0];
  // staging: thread covers row tid>>3 (+32), col (tid&7)*8
  const int rS = tid >> 3, cS = (tid & 7) * 8;
  __bf16* ldsK = sK + tid * 8;
  __bf16* ldsV = sVt + tid * 8;

  for (int phase = 0; phase < 2; ++phase) {
    const int qt = (phase == 0) ? pair : 31 - pair;
    const int q0 = qt * 64;
    bf16x8 qf[2];
    #pragma unroll
    for (int kk = 0; kk < 2; ++kk)
      qf[kk] = *(const bf16x8*)(qg + (size_t)(q0 + w * 16 + l16) * 1024 + hh * 64 + kk * 32 + quad * 8);
    f32x4 accO[4] = {};
    float m_[4], l_[4];
    #pragma unroll
    for (int r = 0; r < 4; ++r) { m_[r] = -INFINITY; l_[r] = 0.f; }

    for (int kt = 0; kt <= qt; ++kt) {
      const __bf16* gK = kg + (size_t)(kt * 64 + rS) * 1024 + hh * 64 + cS;
      const __bf16* gV = vtg + (size_t)(hh * 64 + rS) * 2048 + kt * 64 + cS;
      GLD16(gK, ldsK);
      GLD16(gK + (size_t)32 * 1024, ldsK + 2048);
      GLD16(gV, ldsV);
      GLD16(gV + (size_t)32 * 2048, ldsV + 2048);
      __syncthreads();

      // S = Q K^T  (8 MFMA), rows = w*16+quad*4+r, cols = nt*16+l16
      f32x4 s4[4];
      #pragma unroll
      for (int nt = 0; nt < 4; ++nt) {
        bf16x8 b0 = *(const bf16x8*)(sK + (nt * 16 + l16) * 64 + quad * 8);
        bf16x8 b1 = *(const bf16x8*)(sK + (nt * 16 + l16) * 64 + 32 + quad * 8);
        f32x4 sa = {0.f, 0.f, 0.f, 0.f};
        sa = __builtin_amdgcn_mfma_f32_16x16x32_bf16(qf[0], b0, sa, 0, 0, 0);
        sa = __builtin_amdgcn_mfma_f32_16x16x32_bf16(qf[1], b1, sa, 0, 0, 0);
        s4[nt] = sa;
      }
      if (kt == qt) {  // diagonal tile causal mask
        #pragma unroll
        for (int nt = 0; nt < 4; ++nt)
          #pragma unroll
          for (int r = 0; r < 4; ++r)
            if (nt * 16 + l16 > w * 16 + quad * 4 + r) s4[nt][r] = -INFINITY;
      }
      // register online softmax
      float mx[4], al[4], rs[4];
      #pragma unroll
      for (int r = 0; r < 4; ++r)
        mx[r] = fmaxf(fmaxf(s4[0][r], s4[1][r]), fmaxf(s4[2][r], s4[3][r]));
      #pragma unroll
      for (int o = 1; o < 16; o <<= 1)
        #pragma unroll
        for (int r = 0; r < 4; ++r) mx[r] = fmaxf(mx[r], __shfl_xor(mx[r], o));
      #pragma unroll
      for (int r = 0; r < 4; ++r) {
        float mn = fmaxf(m_[r], mx[r]);
        al[r] = __expf(m_[r] - mn);
        m_[r] = mn;
      }
      float p[4][4];
      #pragma unroll
      for (int nt = 0; nt < 4; ++nt)
        #pragma unroll
        for (int r = 0; r < 4; ++r)
          p[nt][r] = __expf(s4[nt][r] - m_[r]);   // masked: -inf -> 0
      #pragma unroll
      for (int r = 0; r < 4; ++r)
        rs[r] = (p[0][r] + p[1][r]) + (p[2][r] + p[3][r]);
      #pragma unroll
      for (int o = 1; o < 16; o <<= 1)
        #pragma unroll
        for (int r = 0; r < 4; ++r) rs[r] += __shfl_xor(rs[r], o);
      #pragma unroll
      for (int r = 0; r < 4; ++r) l_[r] = l_[r] * al[r] + rs[r];
      #pragma unroll
      for (int nt = 0; nt < 4; ++nt)
        #pragma unroll
        for (int r = 0; r < 4; ++r) accO[nt][r] *= al[r];
      // P -> per-wave LDS region (transpose to A-layout)
      #pragma unroll
      for (int nt = 0; nt < 4; ++nt)
        #pragma unroll
        for (int r = 0; r < 4; ++r)
          sP[(w * 16 + quad * 4 + r) * 72 + nt * 16 + l16] = (__bf16)p[nt][r];
      // O += P V   (wave-private sP: no barrier, compiler emits lgkmcnt wait)
      #pragma unroll
      for (int kk = 0; kk < 2; ++kk) {
        bf16x8 a = *(const bf16x8*)(sP + (w * 16 + l16) * 72 + kk * 32 + quad * 8);
        #pragma unroll
        for (int nt = 0; nt < 4; ++nt) {
          bf16x8 bv = *(const bf16x8*)(sVt + (nt * 16 + l16) * 64 + kk * 32 + quad * 8);
          accO[nt] = __builtin_amdgcn_mfma_f32_16x16x32_bf16(a, bv, accO[nt], 0, 0, 0);
        }
      }
      __syncthreads();
    }
    // epilogue
    #pragma unroll
    for (int nt = 0; nt < 4; ++nt) {
      int dcol = nt * 16 + l16;
      #pragma unroll
      for (int r = 0; r < 4; ++r) {
        int grow = q0 + w * 16 + quad * 4 + r;
        float val = l2s * accO[nt][r] / l_[r] + sbr[grow * 16 + hh];
        yo[(size_t)grow * 1024 + hh * 64 + dcol] = (__bf16)val;
      }
    }
  }
}

// ---------------- SwiGLU: ffin = silu(u[:,4096+i]) * u[:,i], bf16 ----------
__global__ __launch_bounds__(256) void silu_k(const float* __restrict__ u,
                                              __bf16* __restrict__ ffin) {
  int i = blockIdx.x * 256 + threadIdx.x;
  int s = i >> 10, c = (i & 1023) * 4;
  const float4 xp = *(const float4*)(u + (size_t)s * 8192 + c);
  const float4 g  = *(const float4*)(u + (size_t)s * 8192 + 4096 + c);
  __bf16* o = ffin + (size_t)s * 4096 + c;
  o[0] = (__bf16)(xp.x * g.x / (1.f + expf(-g.x)));
  o[1] = (__bf16)(xp.y * g.y / (1.f + expf(-g.y)));
  o[2] = (__bf16)(xp.z * g.z / (1.f + expf(-g.z)));
  o[3] = (__bf16)(xp.w * g.w / (1.f + expf(-g.w)));
}

extern "C" void kernel_launch(void* const* d_in, const int* in_sizes, int n_in,
                              void* d_out, int out_size, void* d_ws, size_t ws_size,
                              hipStream_t stream) {
  (void)in_sizes; (void)n_in; (void)out_size; (void)ws_size;
  const float* hs   = (const float*)d_in[0];
  const float* Wq   = (const float*)d_in[1];
  const float* Wk   = (const float*)d_in[2];
  const float* Wv   = (const float*)d_in[3];
  const float* Wqb  = (const float*)d_in[4];
  const float* Wkb  = (const float*)d_in[5];
  const float* Wo   = (const float*)d_in[6];
  const float* bo   = (const float*)d_in[7];
  const float* W1   = (const float*)d_in[8];
  const float* b1   = (const float*)d_in[9];
  const float* W2   = (const float*)d_in[10];
  const float* b2   = (const float*)d_in[11];
  const float* plam = (const float*)d_in[12];
  const float* pl2s = (const float*)d_in[13];
  float* out = (float*)d_out;
  char* ws = (char*)d_ws;

  size_t off = 0;
  auto alloc = [&](size_t bytes) { char* p = ws + off; off += (bytes + 255) & ~(size_t)255; return p; };
  __bf16* Wt5  = (__bf16*)alloc((size_t)5 * 1024 * 1024 * 2);
  __bf16* Wot  = (__bf16*)alloc((size_t)1024 * 1024 * 2);
  __bf16* W1t  = (__bf16*)alloc((size_t)8192 * 1024 * 2);
  __bf16* W2t  = (__bf16*)alloc((size_t)1024 * 4096 * 2);
  __bf16* xbf  = (__bf16*)alloc((size_t)2048 * 1024 * 2);
  char* ureg = ws + off;  // u (64 MB) aliases [proj,qbf32,kbf32,qbf,kbf]
  float*  proj  = (float*)alloc((size_t)2048 * 5120 * 4);
  float*  qbf32 = (float*)alloc((size_t)2048 * 1024 * 4);
  float*  kbf32 = (float*)alloc((size_t)2048 * 1024 * 4);
  __bf16* qbf   = (__bf16*)alloc((size_t)2048 * 1024 * 2);
  __bf16* kbf   = (__bf16*)alloc((size_t)2048 * 1024 * 2);
  float*  u     = (float*)ureg;
  __bf16* vtbf  = (__bf16*)alloc((size_t)1024 * 2048 * 2);
  __bf16* ybf   = (__bf16*)alloc((size_t)2048 * 1024 * 2);
  float*  sbrow = (float*)alloc((size_t)2048 * 16 * 4);
  float*  tsum  = (float*)alloc((size_t)64 * 16 * 64 * 4);
  float*  attn  = (float*)alloc((size_t)2048 * 1024 * 4);
  __bf16* ffin  = (__bf16*)alloc((size_t)2048 * 4096 * 2);

  tconv_k<<<dim3(32, 32), 256, 0, stream>>>(Wq,  Wt5,               1024, 1024);
  tconv_k<<<dim3(32, 32), 256, 0, stream>>>(Wk,  Wt5 + 1048576,     1024, 1024);
  tconv_k<<<dim3(32, 32), 256, 0, stream>>>(Wv,  Wt5 + 2 * 1048576, 1024, 1024);
  tconv_k<<<dim3(32, 32), 256, 0, stream>>>(Wqb, Wt5 + 3 * 1048576, 1024, 1024);
  tconv_k<<<dim3(32, 32), 256, 0, stream>>>(Wkb, Wt5 + 4 * 1048576, 1024, 1024);
  tconv_k<<<dim3(32, 32), 256, 0, stream>>>(Wo,  Wot,               1024, 1024);
  tconv_k<<<dim3(256, 32), 256, 0, stream>>>(W1, W1t,               8192, 1024);
  tconv_k<<<dim3(32, 128), 256, 0, stream>>>(W2, W2t,               1024, 4096);

  rmsnorm_k<<<2048, 256, 0, stream>>>(hs, xbf);
  gemm_bt_k<<<dim3(40, 16), 256, 0, stream>>>(xbf, Wt5, proj, 5120, 1024,
                                              nullptr, nullptr, nullptr, nullptr);
  qkprep_k<<<8192, 256, 0, stream>>>(proj, qbf, kbf, qbf32, kbf32);
  tconv_k<<<dim3(32, 64), 256, 0, stream>>>(proj + 2048, vtbf, 5120, 2048);
  kbsum_k<<<dim3(64, 16), 64, 0, stream>>>(kbf32, tsum);
  sbrow2_k<<<dim3(64, 16), 64, 0, stream>>>(qbf32, kbf32, tsum, sbrow);
  attn_k<<<dim3(16, 16), 256, 0, stream>>>(qbf, kbf, vtbf, sbrow, pl2s, ybf);
  gemm_bt64_k<<<dim3(16, 16), 256, 0, stream>>>(ybf, Wot, attn, 1024, 1024,
                                                bo, nullptr, nullptr, nullptr);
  gemm_bt_k<<<dim3(64, 16), 256, 0, stream>>>(xbf, W1t, u, 8192, 1024,
                                              b1, nullptr, nullptr, nullptr);
  silu_k<<<8192, 256, 0, stream>>>(u, ffin);
  gemm_bt64_k<<<dim3(16, 16), 256, 0, stream>>>(ffin, W2t, out, 1024, 4096,
                                                b2, attn, hs, plam);
}